// Round 9
// baseline (224.325 us; speedup 1.0000x reference)
//
#include <hip/hip_runtime.h>

// PermuteWeightSharing: out[row, s*16+k] = x[row, ppos[s]*16+k] - x[row, pneg[s]*16+k]
// row = (b,o,i) flattened, 256 floats per row = 16 slots x 16 floats = 64 float4.
//
// v10 = v9 body (best measured: bench 219.4; zero-preamble, sequential
// cycle-0 x-load, per-wave in-register ballot decode, ds_bpermute apply)
// with ONLY the launch shape changed: block 1024 / grid 8192 instead of
// 256 / 32768. Same total threads, same 32-waves/CU ceiling (2 blocks x 16
// waves), but 4x fewer workgroup dispatch/retire events. Theory: measured
// OccupancyPercent has been pinned at 63-65% on every one-shot variant
// (VGPR=20, LDS~0) -- short-lived 4-wave blocks retire faster than the
// CP/SPI refills the 8 block-slots/CU, capping resident TLP at ~2/3 of max.
// Bigger blocks deliver 16 waves per refill event.

#define NSLOTS 16

typedef float fvec4 __attribute__((ext_vector_type(4)));

__device__ inline fvec4 lane_gather(fvec4 a, int byte_addr)
{
    fvec4 r;
    r.x = __int_as_float(__builtin_amdgcn_ds_bpermute(byte_addr, __float_as_int(a.x)));
    r.y = __int_as_float(__builtin_amdgcn_ds_bpermute(byte_addr, __float_as_int(a.y)));
    r.z = __int_as_float(__builtin_amdgcn_ds_bpermute(byte_addr, __float_as_int(a.z)));
    r.w = __int_as_float(__builtin_amdgcn_ds_bpermute(byte_addr, __float_as_int(a.w)));
    return r;
}

// Wave-cooperative one-hot decode: lane l holds float4 #l of a 16x16
// row-major perm matrix (row = l>>2, cols (l&3)*4..+3). Returns the hot
// column of row `slot` == perm[slot].
__device__ inline int decode_col(const fvec4 pr, int slot)
{
    int  h    = 0;
    bool pres = false;
    if (pr.x > 0.5f) { h = 0; pres = true; }
    if (pr.y > 0.5f) { h = 1; pres = true; }
    if (pr.z > 0.5f) { h = 2; pres = true; }
    if (pr.w > 0.5f) { h = 3; pres = true; }
    const unsigned long long bp = __ballot(pres);     // which lane(s) hold row's hot chunk
    const unsigned long long b0 = __ballot(h & 1);    // low bit of within-chunk idx
    const unsigned long long b1 = __ballot(h >> 1);   // high bit
    const int nib = (int)((bp >> (slot * 4)) & 0xFull);      // my row's 4 lanes
    const int cl  = slot * 4 + __builtin_ctz(nib);           // hot chunk's lane
    const int hh  = (int)((b0 >> cl) & 1ull) | ((int)((b1 >> cl) & 1ull) << 1);
    return ((cl & 3) << 2) | hh;                             // col in [0,16)
}

__global__ __launch_bounds__(1024, 2) void permute_ws_kernel(
    const fvec4* __restrict__ x,
    const float* __restrict__ Ppos,
    const float* __restrict__ Pneg,
    fvec4* __restrict__ out,
    int total_v4)
{
    const int t    = threadIdx.x;
    const int lane = t & 63;
    const int i    = blockIdx.x * 1024 + t;   // 1 float4 per thread

    // total_v4 is a multiple of 64 (whole rows), so this guard is
    // wave-uniform: ballots/bpermutes below always see all 64 lanes.
    if (i >= total_v4) return;

    // ---- x load FIRST: sequential, permutation-independent, cycle-0 issue ----
    const fvec4 a = x[i];

    // ---- decode overlaps the x-load latency (no LDS, no barrier) ----
    const fvec4 prp = ((const fvec4*)Ppos)[lane];   // 64 lanes x 16B = whole matrix
    const fvec4 prn = ((const fvec4*)Pneg)[lane];
    const int slot = lane >> 2;
    const int k4   = lane & 3;
    const int colp = decode_col(prp, slot);
    const int coln = decode_col(prn, slot);
    // source lane holding input float4 (4*col + k4); bpermute addr = lane*4
    const int bpa = (((colp << 2) | k4) << 2);
    const int bna = (((coln << 2) | k4) << 2);

    out[i] = lane_gather(a, bpa) - lane_gather(a, bna);
}

extern "C" void kernel_launch(void* const* d_in, const int* in_sizes, int n_in,
                              void* d_out, int out_size, void* d_ws, size_t ws_size,
                              hipStream_t stream)
{
    const fvec4* x    = (const fvec4*)d_in[0];
    const float* Ppos = (const float*)d_in[1];
    const float* Pneg = (const float*)d_in[2];
    fvec4*       out  = (fvec4*)d_out;

    const int total_v4 = out_size / 4;   // 33,554,432 / 4 = 8,388,608

    const int block = 1024;
    const int grid  = (total_v4 + block - 1) / block;   // 8192, exact fit

    permute_ws_kernel<<<grid, block, 0, stream>>>(x, Ppos, Pneg, out, total_v4);
}

// Round 10
// 222.415 us; speedup vs baseline: 1.0086x; 1.0086x over previous
//
#include <hip/hip_runtime.h>

// PermuteWeightSharing: out[row, s*16+k] = x[row, ppos[s]*16+k] - x[row, pneg[s]*16+k]
// row = (b,o,i) flattened, 256 floats per row = 16 slots x 16 floats = 64 float4.
//
// v11: final orthogonal cell. v9 geometry (best: bench 219.4; 32768 blocks
// x 256 thr, 1 float4/thread, zero LDS/barrier) but with the permutation
// applied via direct scattered dual-gather instead of post-load ds_bpermute.
// v9's chain: x-load(cycle0) -> vmcnt -> 8 ds_bpermute -> sub -> store.
// Here:       perm L1-load -> ballot decode (~150cy, L1-hot) ->
//             2 scattered x-gathers -> sub -> store.
// Chain lengths are nominally equal; the delta tests whether 67M bpermute
// instrs of DS-pipe pressure at full occupancy were costing issue cycles.
// (v5 A/B proved scattered gather == sequential load in throughput; v10
// showed 1024-thread blocks regress -- block retirement granularity.)

#define NSLOTS 16

typedef float fvec4 __attribute__((ext_vector_type(4)));

// Wave-cooperative one-hot decode: lane l holds float4 #l of a 16x16
// row-major perm matrix (row = l>>2, cols (l&3)*4..+3). Returns the hot
// column of row `slot` == perm[slot].
__device__ inline int decode_col(const fvec4 pr, int slot)
{
    int  h    = 0;
    bool pres = false;
    if (pr.x > 0.5f) { h = 0; pres = true; }
    if (pr.y > 0.5f) { h = 1; pres = true; }
    if (pr.z > 0.5f) { h = 2; pres = true; }
    if (pr.w > 0.5f) { h = 3; pres = true; }
    const unsigned long long bp = __ballot(pres);     // which lane(s) hold row's hot chunk
    const unsigned long long b0 = __ballot(h & 1);    // low bit of within-chunk idx
    const unsigned long long b1 = __ballot(h >> 1);   // high bit
    const int nib = (int)((bp >> (slot * 4)) & 0xFull);      // my row's 4 lanes
    const int cl  = slot * 4 + __builtin_ctz(nib);           // hot chunk's lane
    const int hh  = (int)((b0 >> cl) & 1ull) | ((int)((b1 >> cl) & 1ull) << 1);
    return ((cl & 3) << 2) | hh;                             // col in [0,16)
}

__global__ __launch_bounds__(256, 8) void permute_ws_kernel(
    const fvec4* __restrict__ x,
    const float* __restrict__ Ppos,
    const float* __restrict__ Pneg,
    fvec4* __restrict__ out,
    int total_v4)
{
    const int t    = threadIdx.x;
    const int lane = t & 63;
    const int i    = blockIdx.x * 256 + t;   // 1 float4 per thread

    // total_v4 is a multiple of 64 (whole rows): guard is wave-uniform.
    if (i >= total_v4) return;

    // ---- decode: perm loads are L1-hot broadcasts after first blocks ----
    const fvec4 prp = ((const fvec4*)Ppos)[lane];   // 64 lanes x 16B = whole matrix
    const fvec4 prn = ((const fvec4*)Pneg)[lane];
    const int slot = lane >> 2;
    const int k4   = lane & 3;
    const int colp = decode_col(prp, slot);
    const int coln = decode_col(prn, slot);

    // ---- scattered dual-gather within this lane's row (64B-block permuted) ----
    const int rb = i & ~63;                     // row base (row-aligned grid)
    const fvec4 a = x[rb + ((colp << 2) | k4)];
    const fvec4 b = x[rb + ((coln << 2) | k4)];

    out[i] = a - b;
}

extern "C" void kernel_launch(void* const* d_in, const int* in_sizes, int n_in,
                              void* d_out, int out_size, void* d_ws, size_t ws_size,
                              hipStream_t stream)
{
    const fvec4* x    = (const fvec4*)d_in[0];
    const float* Ppos = (const float*)d_in[1];
    const float* Pneg = (const float*)d_in[2];
    fvec4*       out  = (fvec4*)d_out;

    const int total_v4 = out_size / 4;   // 33,554,432 / 4 = 8,388,608

    const int block = 256;
    const int grid  = (total_v4 + block - 1) / block;   // 32768, exact fit

    permute_ws_kernel<<<grid, block, 0, stream>>>(x, Ppos, Pneg, out, total_v4);
}